// Round 1
// baseline (690.655 us; speedup 1.0000x reference)
//
#include <hip/hip_runtime.h>
#include <stdint.h>

#define N_NODES 20000
#define K_NB 32
#define D_DIM 128

typedef short bf16x8 __attribute__((ext_vector_type(8)));
typedef float f32x4 __attribute__((ext_vector_type(4)));

// fp32 -> bf16 round-to-nearest-even
__device__ __forceinline__ unsigned short f2bf(float f) {
    union { float f; unsigned u; } v; v.f = f;
    unsigned r = v.u + 0x7FFFu + ((v.u >> 16) & 1u);
    return (unsigned short)(r >> 16);
}

__device__ __forceinline__ bf16x8 pack8(float4 a, float4 b) {
    bf16x8 r;
    r[0] = (short)f2bf(a.x); r[1] = (short)f2bf(a.y);
    r[2] = (short)f2bf(a.z); r[3] = (short)f2bf(a.w);
    r[4] = (short)f2bf(b.x); r[5] = (short)f2bf(b.y);
    r[6] = (short)f2bf(b.z); r[7] = (short)f2bf(b.w);
    return r;
}

__device__ __forceinline__ float dot16(float4 a0, float4 a1, float4 a2, float4 a3,
                                       float4 b0, float4 b1, float4 b2, float4 b3) {
    return a0.x*b0.x + a0.y*b0.y + a0.z*b0.z + a0.w*b0.w
         + a1.x*b1.x + a1.y*b1.y + a1.z*b1.z + a1.w*b1.w
         + a2.x*b2.x + a2.y*b2.y + a2.z*b2.z + a2.w*b2.w
         + a3.x*b3.x + a3.y*b3.y + a3.z*b3.z + a3.w*b3.w;
}

__device__ __forceinline__ float sigm(float x) {
    return __builtin_amdgcn_rcpf(1.0f + __expf(-x));
}

// LDS strides (in elements) chosen to spread banks:
// A (bf16): 136 shorts = 272 B/row -> uniform 8 accesses/bank on ds_read_b128 fragments
// NG (f32): 132 floats = 528 B/row -> 2-way conflicts only on epilogue b32 reads (free)
#define A_STRIDE 136
#define NG_STRIDE 132

// ---------------------------------------------------------------------------
// Kernel 1: tsf[n,e] = self_feats @ self_weights ; ts[n] = self_vecs . gate_self_w
// grid = 625 blocks (32 nodes each), 256 threads
// ---------------------------------------------------------------------------
__global__ __launch_bounds__(256) void precompute_kernel(
    const float* __restrict__ self_feats,
    const float* __restrict__ self_vecs,
    const float* __restrict__ gate_self_w,
    const float* __restrict__ self_weights,
    float* __restrict__ tsf,
    float* __restrict__ ts)
{
    __shared__ __align__(16) unsigned short A[32 * A_STRIDE];

    const int tid  = threadIdx.x;
    const int lane = tid & 63;
    const int w    = tid >> 6;      // wave 0..3
    const int q    = lane >> 4;     // quad 0..3
    const int el   = lane & 15;
    const int row  = tid >> 3;      // 0..31
    const int seg  = tid & 7;       // 0..7 (16-float segment of a row)
    const int node0 = blockIdx.x * 32;

    // self_weights B-fragments: B[d][e], e = 32w+16nt+el, d = 32s+8q+j
    bf16x8 wf[2][4];
#pragma unroll
    for (int nt = 0; nt < 2; ++nt) {
        int e = 32 * w + 16 * nt + el;
#pragma unroll
        for (int s = 0; s < 4; ++s) {
#pragma unroll
            for (int j = 0; j < 8; ++j) {
                int d = 32 * s + 8 * q + j;
                wf[nt][s][j] = (short)f2bf(self_weights[d * 128 + e]);
            }
        }
    }

    // gate_self_w segment in registers
    const float4* gs = (const float4*)(gate_self_w + seg * 16);
    float4 g0 = gs[0], g1 = gs[1], g2 = gs[2], g3 = gs[3];

    // stage self_feats rows (bf16 -> LDS), dot self_vecs row with gate_self_w
    {
        const float4* sfr = (const float4*)(self_feats + (size_t)(node0 + row) * 128 + seg * 16);
        float4 v0 = sfr[0], v1 = sfr[1], v2 = sfr[2], v3 = sfr[3];
        const float4* svr = (const float4*)(self_vecs + (size_t)(node0 + row) * 128 + seg * 16);
        float4 u0 = svr[0], u1 = svr[1], u2 = svr[2], u3 = svr[3];

        float part = dot16(u0, u1, u2, u3, g0, g1, g2, g3);
        part += __shfl_xor(part, 1);
        part += __shfl_xor(part, 2);
        part += __shfl_xor(part, 4);
        if (seg == 0) ts[node0 + row] = part;

        *(bf16x8*)&A[row * A_STRIDE + seg * 16]     = pack8(v0, v1);
        *(bf16x8*)&A[row * A_STRIDE + seg * 16 + 8] = pack8(v2, v3);
    }
    __syncthreads();

    // A fragments: A[m][k], m = 16mt+el, k = 32s+8q+j
    bf16x8 af[2][4];
#pragma unroll
    for (int mt = 0; mt < 2; ++mt)
#pragma unroll
        for (int s = 0; s < 4; ++s)
            af[mt][s] = *(const bf16x8*)&A[(16 * mt + el) * A_STRIDE + 32 * s + 8 * q];

    f32x4 acc[2][2] = {};
#pragma unroll
    for (int mt = 0; mt < 2; ++mt)
#pragma unroll
        for (int nt = 0; nt < 2; ++nt)
#pragma unroll
            for (int s = 0; s < 4; ++s)
                acc[mt][nt] = __builtin_amdgcn_mfma_f32_16x16x32_bf16(
                    af[mt][s], wf[nt][s], acc[mt][nt], 0, 0, 0);

    // C/D layout: col = lane&15, row = 4q + reg
#pragma unroll
    for (int mt = 0; mt < 2; ++mt)
#pragma unroll
        for (int nt = 0; nt < 2; ++nt)
#pragma unroll
            for (int r = 0; r < 4; ++r) {
                int m = 16 * mt + 4 * q + r;
                tsf[(size_t)(node0 + m) * 128 + 32 * w + 16 * nt + el] = acc[mt][nt][r];
            }
}

// ---------------------------------------------------------------------------
// Kernel 2: main fused aggregation. 1024 blocks x 256 threads, ~20 nodes/block.
// Per node: 32x128x128 bf16 MFMA GEMM (trans_links logits) fused with gate,
// importance weighting, K-mean, tsf scaling, relu.
// ---------------------------------------------------------------------------
__global__ __launch_bounds__(256) void aggregate_kernel(
    const float* __restrict__ neigh_vecs,
    const float* __restrict__ link_vecs,
    const float* __restrict__ select_probs,
    const float* __restrict__ gate_neigh_w,
    const float* __restrict__ gate_link_w,
    const float* __restrict__ link_weights,
    const float* __restrict__ tsf,
    const float* __restrict__ ts,
    float* __restrict__ out)
{
    __shared__ __align__(16) unsigned short A[32 * A_STRIDE];
    __shared__ __align__(16) float NG[32 * NG_STRIDE];
    __shared__ float tl_s[32], tn_s[32], gdp_s[32], tsf_s[128];

    const int tid  = threadIdx.x;
    const int lane = tid & 63;
    const int w    = tid >> 6;
    const int q    = lane >> 4;
    const int el   = lane & 15;
    const int row  = tid >> 3;
    const int seg  = tid & 7;

    // link_weights B-fragments held in registers for the whole block
    bf16x8 wf[2][4];
#pragma unroll
    for (int nt = 0; nt < 2; ++nt) {
        int e = 32 * w + 16 * nt + el;
#pragma unroll
        for (int s = 0; s < 4; ++s) {
#pragma unroll
            for (int j = 0; j < 8; ++j) {
                int d = 32 * s + 8 * q + j;
                wf[nt][s][j] = (short)f2bf(link_weights[d * 128 + e]);
            }
        }
    }

    const float4* glp = (const float4*)(gate_link_w + seg * 16);
    float4 gl0 = glp[0], gl1 = glp[1], gl2 = glp[2], gl3 = glp[3];
    const float4* gnp = (const float4*)(gate_neigh_w + seg * 16);
    float4 gn0 = gnp[0], gn1 = gnp[1], gn2 = gnp[2], gn3 = gnp[3];

    for (int n = blockIdx.x; n < N_NODES; n += gridDim.x) {
        __syncthreads();  // protect LDS from previous iteration's epilogue reads

        // prefetch per-node scalars early
        float p_pref = 1.0f, ts_pref = 0.0f;
        if (tid < 32) {
            p_pref  = select_probs[(size_t)n * 32 + tid];
            ts_pref = ts[n];
        }
        if (tid < 128) tsf_s[tid] = tsf[(size_t)n * 128 + tid];

        // ---- stage link row (bf16->LDS) + gate-link dot ----
        const float4* lr = (const float4*)(link_vecs + ((size_t)n * 32 + row) * 128 + seg * 16);
        float4 v0 = lr[0], v1 = lr[1], v2 = lr[2], v3 = lr[3];
        const float4* nr = (const float4*)(neigh_vecs + ((size_t)n * 32 + row) * 128 + seg * 16);
        float4 u0 = nr[0], u1 = nr[1], u2 = nr[2], u3 = nr[3];

        float tl = dot16(v0, v1, v2, v3, gl0, gl1, gl2, gl3);
        tl += __shfl_xor(tl, 1);
        tl += __shfl_xor(tl, 2);
        tl += __shfl_xor(tl, 4);
        float tn = dot16(u0, u1, u2, u3, gn0, gn1, gn2, gn3);
        tn += __shfl_xor(tn, 1);
        tn += __shfl_xor(tn, 2);
        tn += __shfl_xor(tn, 4);
        if (seg == 0) { tl_s[row] = tl; tn_s[row] = tn; }

        *(bf16x8*)&A[row * A_STRIDE + seg * 16]     = pack8(v0, v1);
        *(bf16x8*)&A[row * A_STRIDE + seg * 16 + 8] = pack8(v2, v3);

        float4* ngp = (float4*)&NG[row * NG_STRIDE + seg * 16];
        ngp[0] = u0; ngp[1] = u1; ngp[2] = u2; ngp[3] = u3;

        __syncthreads();  // staging visible

        // gate / (p*K) per neighbor row
        if (tid < 32) {
            float g = sigm(ts_pref + tn_s[tid] + tl_s[tid]);
            gdp_s[tid] = g / (p_pref * 32.0f);
        }

        // ---- MFMA: C[m][e] = link_row_m . W[:,e] ----
        bf16x8 af[2][4];
#pragma unroll
        for (int mt = 0; mt < 2; ++mt)
#pragma unroll
            for (int s = 0; s < 4; ++s)
                af[mt][s] = *(const bf16x8*)&A[(16 * mt + el) * A_STRIDE + 32 * s + 8 * q];

        f32x4 acc[2][2] = {};
#pragma unroll
        for (int mt = 0; mt < 2; ++mt)
#pragma unroll
            for (int nt = 0; nt < 2; ++nt)
#pragma unroll
                for (int s = 0; s < 4; ++s)
                    acc[mt][nt] = __builtin_amdgcn_mfma_f32_16x16x32_bf16(
                        af[mt][s], wf[nt][s], acc[mt][nt], 0, 0, 0);

        __syncthreads();  // gdp_s visible; A-frag reads done

        // ---- epilogue: sigmoid, x neigh, x gate/(32p), reduce over 32 rows ----
#pragma unroll
        for (int nt = 0; nt < 2; ++nt) {
            int c0 = 32 * w + 16 * nt;
            float s = 0.0f;
#pragma unroll
            for (int mt = 0; mt < 2; ++mt)
#pragma unroll
                for (int r = 0; r < 4; ++r) {
                    int m = 16 * mt + 4 * q + r;
                    float t = sigm(acc[mt][nt][r]);
                    s += t * NG[m * NG_STRIDE + c0 + el] * gdp_s[m];
                }
            s += __shfl_xor(s, 16);
            s += __shfl_xor(s, 32);
            if (q == 0) {
                float o = tsf_s[c0 + el] * s;
                out[(size_t)n * 128 + c0 + el] = o > 0.0f ? o : 0.0f;
            }
        }
    }
}

extern "C" void kernel_launch(void* const* d_in, const int* in_sizes, int n_in,
                              void* d_out, int out_size, void* d_ws, size_t ws_size,
                              hipStream_t stream) {
    const float* self_feats   = (const float*)d_in[0];
    const float* self_vecs    = (const float*)d_in[1];
    const float* neigh_vecs   = (const float*)d_in[2];
    const float* link_vecs    = (const float*)d_in[3];
    const float* select_probs = (const float*)d_in[4];
    const float* gate_self_w  = (const float*)d_in[5];
    const float* gate_neigh_w = (const float*)d_in[6];
    const float* gate_link_w  = (const float*)d_in[7];
    const float* self_weights = (const float*)d_in[8];
    const float* link_weights = (const float*)d_in[9];
    float* out = (float*)d_out;

    float* tsf = (float*)d_ws;                       // [N,128] fp32
    float* ts  = tsf + (size_t)N_NODES * D_DIM;      // [N] fp32

    precompute_kernel<<<N_NODES / 32, 256, 0, stream>>>(
        self_feats, self_vecs, gate_self_w, self_weights, tsf, ts);
    aggregate_kernel<<<1024, 256, 0, stream>>>(
        neigh_vecs, link_vecs, select_probs, gate_neigh_w, gate_link_w,
        link_weights, tsf, ts, out);
}

// Round 2
// 654.315 us; speedup vs baseline: 1.0555x; 1.0555x over previous
//
#include <hip/hip_runtime.h>
#include <stdint.h>

#define N_NODES 20000
#define K_NB 32
#define D_DIM 128

typedef short bf16x8 __attribute__((ext_vector_type(8)));
typedef float f32x4 __attribute__((ext_vector_type(4)));

// fp32 -> bf16 round-to-nearest-even
__device__ __forceinline__ unsigned short f2bf(float f) {
    union { float f; unsigned u; } v; v.f = f;
    unsigned r = v.u + 0x7FFFu + ((v.u >> 16) & 1u);
    return (unsigned short)(r >> 16);
}

__device__ __forceinline__ bf16x8 pack8(float4 a, float4 b) {
    bf16x8 r;
    r[0] = (short)f2bf(a.x); r[1] = (short)f2bf(a.y);
    r[2] = (short)f2bf(a.z); r[3] = (short)f2bf(a.w);
    r[4] = (short)f2bf(b.x); r[5] = (short)f2bf(b.y);
    r[6] = (short)f2bf(b.z); r[7] = (short)f2bf(b.w);
    return r;
}

__device__ __forceinline__ float dot16(float4 a0, float4 a1, float4 a2, float4 a3,
                                       float4 b0, float4 b1, float4 b2, float4 b3) {
    return a0.x*b0.x + a0.y*b0.y + a0.z*b0.z + a0.w*b0.w
         + a1.x*b1.x + a1.y*b1.y + a1.z*b1.z + a1.w*b1.w
         + a2.x*b2.x + a2.y*b2.y + a2.z*b2.z + a2.w*b2.w
         + a3.x*b3.x + a3.y*b3.y + a3.z*b3.z + a3.w*b3.w;
}

__device__ __forceinline__ float sigm(float x) {
    return __builtin_amdgcn_rcpf(1.0f + __expf(-x));
}

#define A_STRIDE 136
#define NG_STRIDE 132

// ---------------------------------------------------------------------------
// Kernel 1: tsf[n,e] = self_feats @ self_weights ; ts[n] = self_vecs . gate_self_w
// ---------------------------------------------------------------------------
__global__ __launch_bounds__(256) void precompute_kernel(
    const float* __restrict__ self_feats,
    const float* __restrict__ self_vecs,
    const float* __restrict__ gate_self_w,
    const float* __restrict__ self_weights,
    float* __restrict__ tsf,
    float* __restrict__ ts)
{
    __shared__ __align__(16) unsigned short A[32 * A_STRIDE];

    const int tid  = threadIdx.x;
    const int lane = tid & 63;
    const int w    = tid >> 6;
    const int q    = lane >> 4;
    const int el   = lane & 15;
    const int row  = tid >> 3;
    const int seg  = tid & 7;
    const int node0 = blockIdx.x * 32;

    bf16x8 wf[2][4];
#pragma unroll
    for (int nt = 0; nt < 2; ++nt) {
        int e = 32 * w + 16 * nt + el;
#pragma unroll
        for (int s = 0; s < 4; ++s) {
#pragma unroll
            for (int j = 0; j < 8; ++j) {
                int d = 32 * s + 8 * q + j;
                wf[nt][s][j] = (short)f2bf(self_weights[d * 128 + e]);
            }
        }
    }

    const float4* gs = (const float4*)(gate_self_w + seg * 16);
    float4 g0 = gs[0], g1 = gs[1], g2 = gs[2], g3 = gs[3];

    {
        const float4* sfr = (const float4*)(self_feats + (size_t)(node0 + row) * 128 + seg * 16);
        float4 v0 = sfr[0], v1 = sfr[1], v2 = sfr[2], v3 = sfr[3];
        const float4* svr = (const float4*)(self_vecs + (size_t)(node0 + row) * 128 + seg * 16);
        float4 u0 = svr[0], u1 = svr[1], u2 = svr[2], u3 = svr[3];

        float part = dot16(u0, u1, u2, u3, g0, g1, g2, g3);
        part += __shfl_xor(part, 1);
        part += __shfl_xor(part, 2);
        part += __shfl_xor(part, 4);
        if (seg == 0) ts[node0 + row] = part;

        *(bf16x8*)&A[row * A_STRIDE + seg * 16]     = pack8(v0, v1);
        *(bf16x8*)&A[row * A_STRIDE + seg * 16 + 8] = pack8(v2, v3);
    }
    __syncthreads();

    bf16x8 af[2][4];
#pragma unroll
    for (int mt = 0; mt < 2; ++mt)
#pragma unroll
        for (int s = 0; s < 4; ++s)
            af[mt][s] = *(const bf16x8*)&A[(16 * mt + el) * A_STRIDE + 32 * s + 8 * q];

    f32x4 acc[2][2] = {};
#pragma unroll
    for (int mt = 0; mt < 2; ++mt)
#pragma unroll
        for (int nt = 0; nt < 2; ++nt)
#pragma unroll
            for (int s = 0; s < 4; ++s)
                acc[mt][nt] = __builtin_amdgcn_mfma_f32_16x16x32_bf16(
                    af[mt][s], wf[nt][s], acc[mt][nt], 0, 0, 0);

#pragma unroll
    for (int mt = 0; mt < 2; ++mt)
#pragma unroll
        for (int nt = 0; nt < 2; ++nt)
#pragma unroll
            for (int r = 0; r < 4; ++r) {
                int m = 16 * mt + 4 * q + r;
                tsf[(size_t)(node0 + m) * 128 + 32 * w + 16 * nt + el] = acc[mt][nt][r];
            }
}

// ---------------------------------------------------------------------------
// Kernel 2: fused aggregation, software-pipelined node loop.
// 2 barriers/node; next node's 32KB global load is in flight during
// MFMA+epilogue of the current node.
// ---------------------------------------------------------------------------
__global__ __launch_bounds__(256) void aggregate_kernel(
    const float* __restrict__ neigh_vecs,
    const float* __restrict__ link_vecs,
    const float* __restrict__ select_probs,
    const float* __restrict__ gate_neigh_w,
    const float* __restrict__ gate_link_w,
    const float* __restrict__ link_weights,
    const float* __restrict__ tsf,
    const float* __restrict__ ts,
    float* __restrict__ out)
{
    __shared__ __align__(16) unsigned short A[32 * A_STRIDE];
    __shared__ __align__(16) float NG[32 * NG_STRIDE];
    __shared__ float t_s[32];    // trans_neigh + trans_link per neighbor
    __shared__ float sp_s[32];   // 1 / (32 * select_prob)

    const int tid  = threadIdx.x;
    const int lane = tid & 63;
    const int w    = tid >> 6;
    const int q    = lane >> 4;
    const int el   = lane & 15;
    const int row  = tid >> 3;
    const int seg  = tid & 7;

    // link_weights B-fragments: registers for the whole block
    bf16x8 wf[2][4];
#pragma unroll
    for (int nt = 0; nt < 2; ++nt) {
        int e = 32 * w + 16 * nt + el;
#pragma unroll
        for (int s = 0; s < 4; ++s) {
#pragma unroll
            for (int j = 0; j < 8; ++j) {
                int d = 32 * s + 8 * q + j;
                wf[nt][s][j] = (short)f2bf(link_weights[d * 128 + e]);
            }
        }
    }

    const float4* glp = (const float4*)(gate_link_w + seg * 16);
    float4 gl0 = glp[0], gl1 = glp[1], gl2 = glp[2], gl3 = glp[3];
    const float4* gnp = (const float4*)(gate_neigh_w + seg * 16);
    float4 gn0 = gnp[0], gn1 = gnp[1], gn2 = gnp[2], gn3 = gnp[3];

    const int stride = gridDim.x;

    // ---- prologue prefetch: node n0 ----
    float4 v0, v1, v2, v3, u0, u1, u2, u3;
    float sp_r = 1.0f, ts_r = 0.0f, tsf_r0 = 0.0f, tsf_r1 = 0.0f;
    {
        int n = blockIdx.x;
        const float4* lr = (const float4*)(link_vecs + ((size_t)n * 32 + row) * 128 + seg * 16);
        v0 = lr[0]; v1 = lr[1]; v2 = lr[2]; v3 = lr[3];
        const float4* nr = (const float4*)(neigh_vecs + ((size_t)n * 32 + row) * 128 + seg * 16);
        u0 = nr[0]; u1 = nr[1]; u2 = nr[2]; u3 = nr[3];
        if (tid < 32) sp_r = select_probs[(size_t)n * 32 + tid];
        ts_r   = ts[n];
        tsf_r0 = tsf[(size_t)n * 128 + 32 * w + el];
        tsf_r1 = tsf[(size_t)n * 128 + 32 * w + 16 + el];
    }

    for (int n = blockIdx.x; n < N_NODES; n += stride) {
        // ---- phase W: stage prefetched regs into LDS + gate dots ----
        float tl = dot16(v0, v1, v2, v3, gl0, gl1, gl2, gl3);
        tl += __shfl_xor(tl, 1);
        tl += __shfl_xor(tl, 2);
        tl += __shfl_xor(tl, 4);
        float tn = dot16(u0, u1, u2, u3, gn0, gn1, gn2, gn3);
        tn += __shfl_xor(tn, 1);
        tn += __shfl_xor(tn, 2);
        tn += __shfl_xor(tn, 4);
        if (seg == 0) t_s[row] = tl + tn;
        if (tid < 32) sp_s[tid] = __builtin_amdgcn_rcpf(32.0f * sp_r);

        *(bf16x8*)&A[row * A_STRIDE + seg * 16]     = pack8(v0, v1);
        *(bf16x8*)&A[row * A_STRIDE + seg * 16 + 8] = pack8(v2, v3);
        float4* ngp = (float4*)&NG[row * NG_STRIDE + seg * 16];
        ngp[0] = u0; ngp[1] = u1; ngp[2] = u2; ngp[3] = u3;

        // keep this node's scalars before the prefetch overwrites the regs
        float ts_cur = ts_r, tc0 = tsf_r0, tc1 = tsf_r1;

        __syncthreads();

        // ---- issue next node's global loads (in flight during compute) ----
        {
            int np = n + stride;
            np = (np < N_NODES) ? np : n;
            const float4* lr = (const float4*)(link_vecs + ((size_t)np * 32 + row) * 128 + seg * 16);
            v0 = lr[0]; v1 = lr[1]; v2 = lr[2]; v3 = lr[3];
            const float4* nr = (const float4*)(neigh_vecs + ((size_t)np * 32 + row) * 128 + seg * 16);
            u0 = nr[0]; u1 = nr[1]; u2 = nr[2]; u3 = nr[3];
            if (tid < 32) sp_r = select_probs[(size_t)np * 32 + tid];
            ts_r   = ts[np];
            tsf_r0 = tsf[(size_t)np * 128 + 32 * w + el];
            tsf_r1 = tsf[(size_t)np * 128 + 32 * w + 16 + el];
        }

        // ---- MFMA: C[m][e] = link_row_m . W[:,e] ----
        bf16x8 af[2][4];
#pragma unroll
        for (int mt = 0; mt < 2; ++mt)
#pragma unroll
            for (int s = 0; s < 4; ++s)
                af[mt][s] = *(const bf16x8*)&A[(16 * mt + el) * A_STRIDE + 32 * s + 8 * q];

        f32x4 acc[2][2] = {};
#pragma unroll
        for (int mt = 0; mt < 2; ++mt)
#pragma unroll
            for (int nt = 0; nt < 2; ++nt)
#pragma unroll
                for (int s = 0; s < 4; ++s)
                    acc[mt][nt] = __builtin_amdgcn_mfma_f32_16x16x32_bf16(
                        af[mt][s], wf[nt][s], acc[mt][nt], 0, 0, 0);

        // ---- per-lane gate weights: g[m] = sigmoid(ts + t[m]) / (32 p[m]) ----
        float g[2][4];
#pragma unroll
        for (int mt = 0; mt < 2; ++mt)
#pragma unroll
            for (int r = 0; r < 4; ++r) {
                int m = 16 * mt + 4 * q + r;
                g[mt][r] = sigm(ts_cur + t_s[m]) * sp_s[m];
            }

        // ---- epilogue: sigmoid(C) * neigh * g, reduce over 32 rows ----
#pragma unroll
        for (int nt = 0; nt < 2; ++nt) {
            int c0 = 32 * w + 16 * nt;
            float s = 0.0f;
#pragma unroll
            for (int mt = 0; mt < 2; ++mt)
#pragma unroll
                for (int r = 0; r < 4; ++r) {
                    int m = 16 * mt + 4 * q + r;
                    float t = sigm(acc[mt][nt][r]);
                    s += t * NG[m * NG_STRIDE + c0 + el] * g[mt][r];
                }
            s += __shfl_xor(s, 16);
            s += __shfl_xor(s, 32);
            if (q == 0) {
                float tc = nt == 0 ? tc0 : tc1;
                float o = tc * s;
                out[(size_t)n * 128 + c0 + el] = o > 0.0f ? o : 0.0f;
            }
        }

        __syncthreads();  // guard LDS against next iteration's phase W
    }
}

extern "C" void kernel_launch(void* const* d_in, const int* in_sizes, int n_in,
                              void* d_out, int out_size, void* d_ws, size_t ws_size,
                              hipStream_t stream) {
    const float* self_feats   = (const float*)d_in[0];
    const float* self_vecs    = (const float*)d_in[1];
    const float* neigh_vecs   = (const float*)d_in[2];
    const float* link_vecs    = (const float*)d_in[3];
    const float* select_probs = (const float*)d_in[4];
    const float* gate_self_w  = (const float*)d_in[5];
    const float* gate_neigh_w = (const float*)d_in[6];
    const float* gate_link_w  = (const float*)d_in[7];
    const float* self_weights = (const float*)d_in[8];
    const float* link_weights = (const float*)d_in[9];
    float* out = (float*)d_out;

    float* tsf = (float*)d_ws;                       // [N,128] fp32
    float* ts  = tsf + (size_t)N_NODES * D_DIM;      // [N] fp32

    precompute_kernel<<<N_NODES / 32, 256, 0, stream>>>(
        self_feats, self_vecs, gate_self_w, self_weights, tsf, ts);
    aggregate_kernel<<<1024, 256, 0, stream>>>(
        neigh_vecs, link_vecs, select_probs, gate_neigh_w, gate_link_w,
        link_weights, tsf, ts, out);
}